// Round 10
// baseline (250.045 us; speedup 1.0000x reference)
//
#include <hip/hip_runtime.h>
#include <hip/hip_fp16.h>

// GCN 2-layer: out = D_in^-1/2 A D_out^-1/2 (relu(D_in^-1/2 A D_out^-1/2 X W1 + b1)) W2 + b2
// Strategy: project-then-aggregate; bucket-partitioned edges, single-pass
// scatter into fixed-capacity bucket regions, per-bucket CSR finalize,
// fused aggregate+GEMM for layer 2.
// R8 354us. R9 FAILED: LDS fp32 atomics (CAS serialization).
// R10 302us. R11 NEUTRAL: MFMA GEMM gain eaten by 1.6M device atomics.
// R12 284us. R13 267us. R14 REGRESSED 272.6us (CU starvation at 128 blocks).
// R15 249us: single-pass partition (~200K device-atomic region reservations).
// R16/R17 245us: fused agg+GEMM. agg_gemm 47.9us with SQ_LDS_BANK_CONFLICT
//     5.6M = EXACTLY the Wt staging loop (8192 2B stores/block in 128
//     wave-ops, row stride 36 dwords = 4 mod 32 -> 8-way). LDS 23KB capped
//     occupancy at 6 blocks/CU.
// R18: (a) agg_gemm: Wt LDS deleted — per-wave B-tile (16 scalar W2 loads)
//     lives in 16 VGPRs, loaded after the gather loop (latency hidden under
//     H-pack + barrier). LDS 23040 -> 4608.
//     (b) H-store packed as one 8B f16x4 store (was 4x2B, 4-way).
//     (c) gemm_scale: k-contiguous staging (thread = (j,kq), f16x8 b128
//     stores -> every bank exactly 8-deep = conflict-free minimum).

static inline size_t align256(size_t x) { return (x + 255) & ~(size_t)255; }

#define BKT_SHIFT 8
#define BKT_W 256              // nodes per bucket window
#define MAX_NBK 400            // LDS sizing guard (N <= 102400)
#define CAP 5120               // per-bucket region capacity (mean 4092, +16s)
#define SC_BLOCKS 256          // scatter blocks (1 per CU)
#define SC_THREADS 512

typedef _Float16 f16x8 __attribute__((ext_vector_type(8)));
typedef _Float16 f16x4 __attribute__((ext_vector_type(4)));
typedef float f32x4 __attribute__((ext_vector_type(4)));

// A: single-pass partition. Per block: LDS hist of slice -> device-atomic
// region reservation (one per touched bucket) -> LDS-cursor scatter.
__global__ __launch_bounds__(SC_THREADS)
void scatter_atomic_kernel(const int* __restrict__ src, const int* __restrict__ dst,
                           int* __restrict__ gcnt_d, int* __restrict__ gcnt_s,
                           int* __restrict__ ebuf, unsigned char* __restrict__ sbuf,
                           int nbk, int E, int slice_len) {
    __shared__ int hd[MAX_NBK];
    __shared__ int hs[MAX_NBK];
    __shared__ int cur_d[MAX_NBK];
    __shared__ int cur_s[MAX_NBK];
    const int b = blockIdx.x;
    const int t = threadIdx.x;
    for (int i = t; i < nbk; i += SC_THREADS) { hd[i] = 0; hs[i] = 0; }
    __syncthreads();
    const int beg = b * slice_len;
    const int end = min(beg + slice_len, E);
    for (int i = beg + t; i < end; i += SC_THREADS) {
        atomicAdd(&hd[dst[i] >> BKT_SHIFT], 1);   // LDS atomic (int: native)
        atomicAdd(&hs[src[i] >> BKT_SHIFT], 1);
    }
    __syncthreads();
    // reserve: ~2*nbk device atomics per block (~200K total, not per-edge)
    for (int i = t; i < nbk; i += SC_THREADS) {
        int c = hd[i];
        cur_d[i] = i * CAP + (c ? atomicAdd(&gcnt_d[i], c) : 0);
        c = hs[i];
        cur_s[i] = i * CAP + (c ? atomicAdd(&gcnt_s[i], c) : 0);
    }
    __syncthreads();
    for (int i = beg + t; i < end; i += SC_THREADS) {  // slice is L2-hot now
        int d = dst[i], s = src[i];
        int pd = atomicAdd(&cur_d[d >> BKT_SHIFT], 1);   // LDS atomic
        ebuf[pd] = ((d & (BKT_W - 1)) << 17) | s;
        int ps = atomicAdd(&cur_s[s >> BKT_SHIFT], 1);   // LDS atomic
        sbuf[ps] = (unsigned char)(s & (BKT_W - 1));
    }
}

// B: per-bucket finalize. db = prefix over gcnt_d (block reduction); emits
// cnt_in, cnt_out, row_ptr, csr_src (contiguous CSR, bucket-local writes).
__global__ __launch_bounds__(256)
void bucket_csr_kernel(const int* __restrict__ ebuf,
                       const unsigned char* __restrict__ sbuf,
                       const int* __restrict__ gcnt_d, const int* __restrict__ gcnt_s,
                       int* __restrict__ csr_src,
                       int* __restrict__ cnt_in, int* __restrict__ cnt_out,
                       int* __restrict__ row_ptr,
                       int nbk, int N, int E) {
    __shared__ int cnt[BKT_W];
    __shared__ int rp[BKT_W];
    __shared__ int cur[BKT_W];
    __shared__ int cnts[BKT_W];
    __shared__ int red[256];
    __shared__ int sh_db;
    const int k = blockIdx.x;
    const int lo = k << BKT_SHIFT;
    const int span = min(BKT_W, N - lo);
    const int t = threadIdx.x;

    // db = sum gcnt_d[0..k)
    int s1 = 0;
    for (int i = t; i < k; i += 256) s1 += gcnt_d[i];
    red[t] = s1;
    __syncthreads();
    for (int off = 128; off >= 1; off >>= 1) {
        if (t < off) red[t] += red[t + off];
        __syncthreads();
    }
    if (t == 0) sh_db = red[0];
    __syncthreads();
    const int db = sh_db;
    const int eb = k * CAP, ee = eb + gcnt_d[k];
    const int sb = k * CAP, se = sb + gcnt_s[k];

    cnt[t] = 0; cnts[t] = 0;
    __syncthreads();
    for (int i = eb + t; i < ee; i += 256) atomicAdd(&cnt[ebuf[i] >> 17], 1);
    for (int i = sb + t; i < se; i += 256) atomicAdd(&cnts[sbuf[i]], 1);
    __syncthreads();
    rp[t] = cnt[t];
    __syncthreads();
    for (int off = 1; off < BKT_W; off <<= 1) {
        int v = (t >= off) ? rp[t - off] : 0;
        __syncthreads();
        rp[t] += v;
        __syncthreads();
    }
    if (t < span) {
        row_ptr[lo + t] = db + rp[t] - cnt[t];
        cnt_in[lo + t]  = cnt[t];
        cnt_out[lo + t] = cnts[t];
    }
    __syncthreads();
    cur[t] = db + rp[t] - cnt[t];
    __syncthreads();
    for (int i = eb + t; i < ee; i += 256) {
        int p = ebuf[i];
        int pos = atomicAdd(&cur[p >> 17], 1);           // LDS atomic
        csr_src[pos] = p & 0x1FFFF;
    }
    if (k == 0 && t == 0) row_ptr[N] = E;
}

// MFMA GEMM: Y[n][j] = (sum_k X[n][k] * W[k][j]) * rsqrt(max(cnt_out[n],1)),
// stored fp16. hi/lo fp16 split (error ~2^-22), fp32 accumulate.
// Staging is k-contiguous per thread -> b128 LDS writes, every bank exactly
// 8-deep (the 64-lane x 16B minimum) = conflict-free.
template <int K>
__global__ __launch_bounds__(256)
void gemm_scale_kernel(const float* __restrict__ X, const float* __restrict__ W,
                       const int* __restrict__ cnt_out,
                       __half* __restrict__ Y, int N) {
    __shared__ _Float16 Wt[2][64][K + 8];   // [hi/lo][col][k]
    const int t = threadIdx.x;
    {
        const int jj = t >> 2;             // column 0..63
        const int kb = (t & 3) * (K / 4);  // k-range base
#pragma unroll
        for (int c8 = 0; c8 < K / 4; c8 += 8) {
            float w[8];
#pragma unroll
            for (int m = 0; m < 8; ++m) w[m] = W[(kb + c8 + m) * 64 + jj];
            f16x8 hi8, lo8;
#pragma unroll
            for (int m = 0; m < 8; ++m) {
                const _Float16 h = (_Float16)w[m];
                hi8[m] = h;
                lo8[m] = (_Float16)(w[m] - (float)h);
            }
            *(f16x8*)&Wt[0][jj][kb + c8] = hi8;
            *(f16x8*)&Wt[1][jj][kb + c8] = lo8;
        }
    }
    __syncthreads();

    const int wid  = t >> 6;
    const int lane = t & 63;
    const int col  = lane & 15;
    const int kg   = (lane >> 4) * 8;

    const int rowA = blockIdx.x * 64 + wid * 16 + col;   // A-frag row
    const size_t xbase = (size_t)min(rowA, N - 1) * K;

    f32x4 acc0 = {}, acc1 = {}, acc2 = {}, acc3 = {};

#pragma unroll
    for (int ks = 0; ks < K; ks += 32) {
        float4 xa = *(const float4*)&X[xbase + ks + kg];
        float4 xb = *(const float4*)&X[xbase + ks + kg + 4];
        const float xs[8] = {xa.x, xa.y, xa.z, xa.w, xb.x, xb.y, xb.z, xb.w};
        f16x8 ahi, alo;
#pragma unroll
        for (int j = 0; j < 8; ++j) {
            const _Float16 h = (_Float16)xs[j];
            ahi[j] = h;
            alo[j] = (_Float16)(xs[j] - (float)h);
        }
#pragma unroll
        for (int tile = 0; tile < 4; ++tile) {
            const f16x8 bhi = *(const f16x8*)&Wt[0][col + 16 * tile][ks + kg];
            const f16x8 blo = *(const f16x8*)&Wt[1][col + 16 * tile][ks + kg];
            f32x4* acc = (tile == 0) ? &acc0 : (tile == 1) ? &acc1
                       : (tile == 2) ? &acc2 : &acc3;
            *acc = __builtin_amdgcn_mfma_f32_16x16x32_f16(ahi, bhi, *acc, 0, 0, 0);
            *acc = __builtin_amdgcn_mfma_f32_16x16x32_f16(alo, bhi, *acc, 0, 0, 0);
            *acc = __builtin_amdgcn_mfma_f32_16x16x32_f16(ahi, blo, *acc, 0, 0, 0);
        }
    }

    // D layout: col = lane&15, row = (lane>>4)*4 + reg   [m89-verified]
    const int rbase = blockIdx.x * 64 + wid * 16 + (lane >> 4) * 4;
#pragma unroll
    for (int r = 0; r < 4; ++r) {
        const int rr = rbase + r;
        if (rr < N) {
            const float sc = rsqrtf((float)max(cnt_out[rr], 1));
            __half* yp = &Y[(size_t)rr * 64 + col];
            yp[0]  = __float2half_rn(acc0[r] * sc);
            yp[16] = __float2half_rn(acc1[r] * sc);
            yp[32] = __float2half_rn(acc2[r] * sc);
            yp[48] = __float2half_rn(acc3[r] * sc);
        }
    }
}

// FUSED layer-1 aggregate + layer-2 GEMM. Block = 16 nodes, 256 threads.
// Phase 1 (16 lanes/node, batch-12 clamped gathers): h = relu(agg*rs_in+b1),
// hi/lo fp16 packed into LDS via single 8B f16x4 stores.
// B-tile (W2) per wave lives in 16 VGPRs: 16 scalar global loads issued
// right after the gather loop (latency hides under H-pack + barrier).
// Phase 2: wave w computes output col-tile 16w..16w+15 for all 16 nodes via
// mfma_f32_16x16x32_f16 (3-term hi/lo, fp32 acc), scaled by rs_out -> Y2.
// No early returns (clamped node ids) so barriers stay uniform.
__global__ __launch_bounds__(256)
void agg_gemm_kernel(const __half* __restrict__ Y,
                     const int* __restrict__ row_ptr,
                     const int* __restrict__ csr_src,
                     const int* __restrict__ cnt_in,
                     const int* __restrict__ cnt_out,
                     const float* __restrict__ b1,
                     const float* __restrict__ W2,
                     __half* __restrict__ Y2, int N) {
    __shared__ _Float16 Hh[16][72];
    __shared__ _Float16 Hl[16][72];
    const int t = threadIdx.x;
    const int wid  = t >> 6;
    const int lane = t & 63;
    const int col  = lane & 15;
    const int kg   = (lane >> 4) * 8;

    // ---- phase 1: aggregate (identical structure to aggregate_kernel) ----
    const int nl = t >> 4;                 // local node 0..15
    const int fq = t & 15;                 // features 4*fq .. 4*fq+3
    const int n  = blockIdx.x * 16 + nl;
    const int nc = min(n, N - 1);

    const int start = row_ptr[nc];
    const int end   = row_ptr[nc + 1];
    const int last  = end - 1;

    float4 acc = {0.f, 0.f, 0.f, 0.f};
    for (int e = start; e < end; e += 12) {
        int idx[12];
#pragma unroll
        for (int j = 0; j < 12; ++j) idx[j] = csr_src[min(e + j, last)];
        uint2 v[12];
#pragma unroll
        for (int j = 0; j < 12; ++j)
            v[j] = *((const uint2*)(Y + ((size_t)idx[j] << 6)) + fq);
#pragma unroll
        for (int j = 0; j < 12; ++j) {
            if (e + j < end) {
                float2 a = __half22float2(*(const __half2*)&v[j].x);
                float2 b = __half22float2(*(const __half2*)&v[j].y);
                acc.x += a.x; acc.y += a.y; acc.z += b.x; acc.w += b.y;
            }
        }
    }

    // issue B-tile loads now: W2[k][16*wid+col], k = kg..kg+7 and 32+kg..+7.
    // Latency hides under the H-pack VALU + barrier below.
    float wb[16];
#pragma unroll
    for (int m = 0; m < 8; ++m) {
        wb[m]     = W2[(kg + m) * 64 + 16 * wid + col];
        wb[m + 8] = W2[(32 + kg + m) * 64 + 16 * wid + col];
    }

    {
        const float sc = rsqrtf((float)max(cnt_in[nc], 1));
        const float4 bb = *(const float4*)&b1[4 * fq];
        float hv[4];
        hv[0] = fmaxf(acc.x * sc + bb.x, 0.f);
        hv[1] = fmaxf(acc.y * sc + bb.y, 0.f);
        hv[2] = fmaxf(acc.z * sc + bb.z, 0.f);
        hv[3] = fmaxf(acc.w * sc + bb.w, 0.f);
        f16x4 hh, hl;
#pragma unroll
        for (int q = 0; q < 4; ++q) {
            const _Float16 hi = (_Float16)hv[q];
            hh[q] = hi;
            hl[q] = (_Float16)(hv[q] - (float)hi);
        }
        *(f16x4*)&Hh[nl][4 * fq] = hh;     // one 8B store (balanced banks)
        *(f16x4*)&Hl[nl][4 * fq] = hl;
    }
    __syncthreads();

    // ---- phase 2: 16x64 @ 64x64 MFMA, wave w -> col tile w ----
    f16x8 bhi0, blo0, bhi1, blo1;
#pragma unroll
    for (int m = 0; m < 8; ++m) {
        _Float16 h = (_Float16)wb[m];
        bhi0[m] = h;
        blo0[m] = (_Float16)(wb[m] - (float)h);
        h = (_Float16)wb[m + 8];
        bhi1[m] = h;
        blo1[m] = (_Float16)(wb[m + 8] - (float)h);
    }

    const f16x8 ahi0 = *(const f16x8*)&Hh[col][kg];
    const f16x8 alo0 = *(const f16x8*)&Hl[col][kg];
    const f16x8 ahi1 = *(const f16x8*)&Hh[col][32 + kg];
    const f16x8 alo1 = *(const f16x8*)&Hl[col][32 + kg];

    f32x4 acc2 = {};
    acc2 = __builtin_amdgcn_mfma_f32_16x16x32_f16(ahi0, bhi0, acc2, 0, 0, 0);
    acc2 = __builtin_amdgcn_mfma_f32_16x16x32_f16(alo0, bhi0, acc2, 0, 0, 0);
    acc2 = __builtin_amdgcn_mfma_f32_16x16x32_f16(ahi0, blo0, acc2, 0, 0, 0);
    acc2 = __builtin_amdgcn_mfma_f32_16x16x32_f16(ahi1, bhi1, acc2, 0, 0, 0);
    acc2 = __builtin_amdgcn_mfma_f32_16x16x32_f16(alo1, bhi1, acc2, 0, 0, 0);
    acc2 = __builtin_amdgcn_mfma_f32_16x16x32_f16(ahi1, blo1, acc2, 0, 0, 0);

    // D layout: col = lane&15, row = (lane>>4)*4 + reg
    const int rloc = (lane >> 4) * 4;
#pragma unroll
    for (int r = 0; r < 4; ++r) {
        const int rr = blockIdx.x * 16 + rloc + r;
        if (rr < N) {
            const float s2 = rsqrtf((float)max(cnt_out[rr], 1));
            Y2[(size_t)rr * 64 + 16 * wid + col] = __float2half_rn(acc2[r] * s2);
        }
    }
}

// out[n][f] = (sum_{in-edges} Y[src][f]) * rsqrt(max(cnt_in[n],1)) + bias[f]
// 16 lanes per node (4 nodes/wave); lane = 2 half2 feature pairs (8B gather).
template <bool RELU>
__global__ __launch_bounds__(256)
void aggregate_kernel(const __half* __restrict__ Y,
                      const int* __restrict__ row_ptr,
                      const int* __restrict__ csr_src,
                      const int* __restrict__ cnt_in,
                      const float* __restrict__ bias,
                      float* __restrict__ out, int N) {
    const int n = blockIdx.x * 16 + (threadIdx.x >> 4);
    if (n >= N) return;
    const int fq = threadIdx.x & 15;          // features 4*fq .. 4*fq+3

    const int start = row_ptr[n];
    const int end   = row_ptr[n + 1];
    const int last  = end - 1;

    float4 acc = {0.f, 0.f, 0.f, 0.f};
    for (int e = start; e < end; e += 12) {
        int idx[12];
#pragma unroll
        for (int j = 0; j < 12; ++j) idx[j] = csr_src[min(e + j, last)];
        uint2 v[12];
#pragma unroll
        for (int j = 0; j < 12; ++j)
            v[j] = *((const uint2*)(Y + ((size_t)idx[j] << 6)) + fq);
#pragma unroll
        for (int j = 0; j < 12; ++j) {
            if (e + j < end) {
                float2 a = __half22float2(*(const __half2*)&v[j].x);
                float2 b = __half22float2(*(const __half2*)&v[j].y);
                acc.x += a.x; acc.y += a.y; acc.z += b.x; acc.w += b.y;
            }
        }
    }

    const float sc = rsqrtf((float)max(cnt_in[n], 1));
    const float4 bb = *(const float4*)&bias[4 * fq];
    float4 o;
    o.x = acc.x * sc + bb.x;
    o.y = acc.y * sc + bb.y;
    o.z = acc.z * sc + bb.z;
    o.w = acc.w * sc + bb.w;
    if (RELU) {
        o.x = fmaxf(o.x, 0.f); o.y = fmaxf(o.y, 0.f);
        o.z = fmaxf(o.z, 0.f); o.w = fmaxf(o.w, 0.f);
    }
    *(float4*)&out[((size_t)n << 6) + 4 * fq] = o;
}

extern "C" void kernel_launch(void* const* d_in, const int* in_sizes, int n_in,
                              void* d_out, int out_size, void* d_ws, size_t ws_size,
                              hipStream_t stream) {
    const float* x   = (const float*)d_in[0];
    const int*   src = (const int*)d_in[1];
    const int*   dst = (const int*)d_in[2];
    const float* W1  = (const float*)d_in[3];
    const float* b1  = (const float*)d_in[4];
    const float* W2  = (const float*)d_in[5];
    const float* b2  = (const float*)d_in[6];
    float* out = (float*)d_out;

    const int N = in_sizes[0] / 128;   // 100000
    const int E = in_sizes[1];         // 1600000

    const int nbk = (N + BKT_W - 1) >> BKT_SHIFT;          // 391 buckets

    // Workspace (~45 MB of ~268 MB). d_out written only by the final agg.
    char* ws = (char*)d_ws;
    size_t off = 0;
    __half* Y       = (__half*)(ws + off); off = align256(off + (size_t)N * 64 * sizeof(__half));
    __half* Y2      = (__half*)(ws + off); off = align256(off + (size_t)N * 64 * sizeof(__half));
    int* csr_src    = (int*)(ws + off);    off = align256(off + (size_t)E * sizeof(int));
    int* ebuf       = (int*)(ws + off);    off = align256(off + (size_t)nbk * CAP * sizeof(int));
    unsigned char* sbuf = (unsigned char*)(ws + off); off = align256(off + (size_t)nbk * CAP);
    int* gcnt       = (int*)(ws + off);    off = align256(off + (size_t)2 * nbk * sizeof(int));
    int* gcnt_d     = gcnt;
    int* gcnt_s     = gcnt + nbk;
    int* cnt_out    = (int*)(ws + off);    off = align256(off + (size_t)N * sizeof(int));
    int* cnt_in     = (int*)(ws + off);    off = align256(off + (size_t)N * sizeof(int));
    int* row_ptr    = (int*)(ws + off);    off = align256(off + (size_t)(N + 1) * sizeof(int));

    const int pslice = (E + SC_BLOCKS - 1) / SC_BLOCKS;

    // Single-pass bucket partition (region counters zeroed first, one fill)
    hipMemsetAsync(gcnt, 0, (size_t)2 * nbk * sizeof(int), stream);
    scatter_atomic_kernel<<<SC_BLOCKS, SC_THREADS, 0, stream>>>(
        src, dst, gcnt_d, gcnt_s, ebuf, sbuf, nbk, E, pslice);
    bucket_csr_kernel<<<nbk, 256, 0, stream>>>(ebuf, sbuf, gcnt_d, gcnt_s, csr_src,
                                               cnt_in, cnt_out, row_ptr, nbk, N, E);

    const int gemm_blocks = (N + 63) / 64;
    const int agg_blocks  = (N + 15) / 16;

    // Layer 1 GEMM: Y = fp16[(X @ W1) * rs_out]
    gemm_scale_kernel<128><<<gemm_blocks, 256, 0, stream>>>(x, W1, cnt_out, Y, N);
    // Fused: agg1 (+b1, relu) -> hidden in LDS -> @W2 * rs_out -> Y2 fp16
    agg_gemm_kernel<<<agg_blocks, 256, 0, stream>>>(Y, row_ptr, csr_src,
                                                    cnt_in, cnt_out, b1, W2, Y2, N);
    // Layer 2 aggregate: out = agg(Y2) * rs_in + b2
    aggregate_kernel<false><<<agg_blocks, 256, 0, stream>>>(Y2, row_ptr, csr_src,
                                                            cnt_in, b2, out, N);
}

// Round 11
// 240.564 us; speedup vs baseline: 1.0394x; 1.0394x over previous
//
#include <hip/hip_runtime.h>
#include <hip/hip_fp16.h>

// GCN 2-layer: out = D_in^-1/2 A D_out^-1/2 (relu(D_in^-1/2 A D_out^-1/2 X W1 + b1)) W2 + b2
// Strategy: project-then-aggregate; bucket-partitioned edges, single-pass
// scatter into fixed-capacity bucket regions, per-bucket CSR finalize,
// fused aggregate+GEMM for layer 2.
// R8 354us. R9 FAILED: LDS fp32 atomics (CAS serialization).
// R10 302us. R11 NEUTRAL: MFMA GEMM gain eaten by 1.6M device atomics.
// R12 284us. R13 267us. R14 REGRESSED 272.6us (CU starvation at 128 blocks).
// R15 249us: single-pass partition (~200K device-atomic region reservations).
// R16/R17 245us: fused agg+GEMM (hidden never in HBM).
// R18 250us (noise): Wt-conflict fix landed (5.6M -> 400K conflicts) but
//     wasn't critical path — agg_gemm still 45us at VALUBusy 40%: per-edge
//     cvt/add VALU + 16-lane addr math dominates.
// R19: (a) both aggregates use 16B uint4 gathers — 8 lanes/node, 32 nodes/
//     block, batch 8: addr VALU and load-issues halve per edge, idx dup
//     halves, 128B/lane in flight. (b) fused H-store = two f16x8 b128
//     stores (bank-minimum). (c) bucket_csr at 512 threads (was 1.5
//     waves/SIMD occupancy; halves pass iterations).

static inline size_t align256(size_t x) { return (x + 255) & ~(size_t)255; }

#define BKT_SHIFT 8
#define BKT_W 256              // nodes per bucket window
#define MAX_NBK 400            // LDS sizing guard (N <= 102400)
#define CAP 5120               // per-bucket region capacity (mean 4092, +16s)
#define SC_BLOCKS 256          // scatter blocks (1 per CU)
#define SC_THREADS 512

typedef _Float16 f16x8 __attribute__((ext_vector_type(8)));
typedef float f32x4 __attribute__((ext_vector_type(4)));

// A: single-pass partition. Per block: LDS hist of slice -> device-atomic
// region reservation (one per touched bucket) -> LDS-cursor scatter.
__global__ __launch_bounds__(SC_THREADS)
void scatter_atomic_kernel(const int* __restrict__ src, const int* __restrict__ dst,
                           int* __restrict__ gcnt_d, int* __restrict__ gcnt_s,
                           int* __restrict__ ebuf, unsigned char* __restrict__ sbuf,
                           int nbk, int E, int slice_len) {
    __shared__ int hd[MAX_NBK];
    __shared__ int hs[MAX_NBK];
    __shared__ int cur_d[MAX_NBK];
    __shared__ int cur_s[MAX_NBK];
    const int b = blockIdx.x;
    const int t = threadIdx.x;
    for (int i = t; i < nbk; i += SC_THREADS) { hd[i] = 0; hs[i] = 0; }
    __syncthreads();
    const int beg = b * slice_len;
    const int end = min(beg + slice_len, E);
    for (int i = beg + t; i < end; i += SC_THREADS) {
        atomicAdd(&hd[dst[i] >> BKT_SHIFT], 1);   // LDS atomic (int: native)
        atomicAdd(&hs[src[i] >> BKT_SHIFT], 1);
    }
    __syncthreads();
    // reserve: ~2*nbk device atomics per block (~200K total, not per-edge)
    for (int i = t; i < nbk; i += SC_THREADS) {
        int c = hd[i];
        cur_d[i] = i * CAP + (c ? atomicAdd(&gcnt_d[i], c) : 0);
        c = hs[i];
        cur_s[i] = i * CAP + (c ? atomicAdd(&gcnt_s[i], c) : 0);
    }
    __syncthreads();
    for (int i = beg + t; i < end; i += SC_THREADS) {  // slice is L2-hot now
        int d = dst[i], s = src[i];
        int pd = atomicAdd(&cur_d[d >> BKT_SHIFT], 1);   // LDS atomic
        ebuf[pd] = ((d & (BKT_W - 1)) << 17) | s;
        int ps = atomicAdd(&cur_s[s >> BKT_SHIFT], 1);   // LDS atomic
        sbuf[ps] = (unsigned char)(s & (BKT_W - 1));
    }
}

// B: per-bucket finalize (512 threads). db = prefix over gcnt_d; emits
// cnt_in, cnt_out, row_ptr, csr_src (contiguous CSR, bucket-local writes).
__global__ __launch_bounds__(512)
void bucket_csr_kernel(const int* __restrict__ ebuf,
                       const unsigned char* __restrict__ sbuf,
                       const int* __restrict__ gcnt_d, const int* __restrict__ gcnt_s,
                       int* __restrict__ csr_src,
                       int* __restrict__ cnt_in, int* __restrict__ cnt_out,
                       int* __restrict__ row_ptr,
                       int nbk, int N, int E) {
    __shared__ int cnt[BKT_W];
    __shared__ int rp[BKT_W];
    __shared__ int cur[BKT_W];
    __shared__ int cnts[BKT_W];
    __shared__ int red[512];
    __shared__ int sh_db;
    const int k = blockIdx.x;
    const int lo = k << BKT_SHIFT;
    const int span = min(BKT_W, N - lo);
    const int t = threadIdx.x;

    // db = sum gcnt_d[0..k)
    int s1 = 0;
    for (int i = t; i < k; i += 512) s1 += gcnt_d[i];
    red[t] = s1;
    __syncthreads();
    for (int off = 256; off >= 1; off >>= 1) {
        if (t < off) red[t] += red[t + off];
        __syncthreads();
    }
    if (t == 0) sh_db = red[0];
    __syncthreads();
    const int db = sh_db;
    const int eb = k * CAP, ee = eb + gcnt_d[k];
    const int sb = k * CAP, se = sb + gcnt_s[k];

    if (t < BKT_W) { cnt[t] = 0; cnts[t] = 0; }
    __syncthreads();
    for (int i = eb + t; i < ee; i += 512) atomicAdd(&cnt[ebuf[i] >> 17], 1);
    for (int i = sb + t; i < se; i += 512) atomicAdd(&cnts[sbuf[i]], 1);
    __syncthreads();
    if (t < BKT_W) rp[t] = cnt[t];
    __syncthreads();
    for (int off = 1; off < BKT_W; off <<= 1) {
        int v = (t < BKT_W && t >= off) ? rp[t - off] : 0;
        __syncthreads();
        if (t < BKT_W) rp[t] += v;
        __syncthreads();
    }
    if (t < span) {
        row_ptr[lo + t] = db + rp[t] - cnt[t];
        cnt_in[lo + t]  = cnt[t];
        cnt_out[lo + t] = cnts[t];
    }
    __syncthreads();
    if (t < BKT_W) cur[t] = db + rp[t] - cnt[t];
    __syncthreads();
    for (int i = eb + t; i < ee; i += 512) {
        int p = ebuf[i];
        int pos = atomicAdd(&cur[p >> 17], 1);           // LDS atomic
        csr_src[pos] = p & 0x1FFFF;
    }
    if (k == 0 && t == 0) row_ptr[N] = E;
}

// MFMA GEMM: Y[n][j] = (sum_k X[n][k] * W[k][j]) * rsqrt(max(cnt_out[n],1)),
// stored fp16. hi/lo fp16 split (error ~2^-22), fp32 accumulate.
// k-contiguous b128 LDS staging = conflict-free minimum.
template <int K>
__global__ __launch_bounds__(256)
void gemm_scale_kernel(const float* __restrict__ X, const float* __restrict__ W,
                       const int* __restrict__ cnt_out,
                       __half* __restrict__ Y, int N) {
    __shared__ _Float16 Wt[2][64][K + 8];   // [hi/lo][col][k]
    const int t = threadIdx.x;
    {
        const int jj = t >> 2;             // column 0..63
        const int kb = (t & 3) * (K / 4);  // k-range base
#pragma unroll
        for (int c8 = 0; c8 < K / 4; c8 += 8) {
            float w[8];
#pragma unroll
            for (int m = 0; m < 8; ++m) w[m] = W[(kb + c8 + m) * 64 + jj];
            f16x8 hi8, lo8;
#pragma unroll
            for (int m = 0; m < 8; ++m) {
                const _Float16 h = (_Float16)w[m];
                hi8[m] = h;
                lo8[m] = (_Float16)(w[m] - (float)h);
            }
            *(f16x8*)&Wt[0][jj][kb + c8] = hi8;
            *(f16x8*)&Wt[1][jj][kb + c8] = lo8;
        }
    }
    __syncthreads();

    const int wid  = t >> 6;
    const int lane = t & 63;
    const int col  = lane & 15;
    const int kg   = (lane >> 4) * 8;

    const int rowA = blockIdx.x * 64 + wid * 16 + col;   // A-frag row
    const size_t xbase = (size_t)min(rowA, N - 1) * K;

    f32x4 acc0 = {}, acc1 = {}, acc2 = {}, acc3 = {};

#pragma unroll
    for (int ks = 0; ks < K; ks += 32) {
        float4 xa = *(const float4*)&X[xbase + ks + kg];
        float4 xb = *(const float4*)&X[xbase + ks + kg + 4];
        const float xs[8] = {xa.x, xa.y, xa.z, xa.w, xb.x, xb.y, xb.z, xb.w};
        f16x8 ahi, alo;
#pragma unroll
        for (int j = 0; j < 8; ++j) {
            const _Float16 h = (_Float16)xs[j];
            ahi[j] = h;
            alo[j] = (_Float16)(xs[j] - (float)h);
        }
#pragma unroll
        for (int tile = 0; tile < 4; ++tile) {
            const f16x8 bhi = *(const f16x8*)&Wt[0][col + 16 * tile][ks + kg];
            const f16x8 blo = *(const f16x8*)&Wt[1][col + 16 * tile][ks + kg];
            f32x4* acc = (tile == 0) ? &acc0 : (tile == 1) ? &acc1
                       : (tile == 2) ? &acc2 : &acc3;
            *acc = __builtin_amdgcn_mfma_f32_16x16x32_f16(ahi, bhi, *acc, 0, 0, 0);
            *acc = __builtin_amdgcn_mfma_f32_16x16x32_f16(alo, bhi, *acc, 0, 0, 0);
            *acc = __builtin_amdgcn_mfma_f32_16x16x32_f16(ahi, blo, *acc, 0, 0, 0);
        }
    }

    // D layout: col = lane&15, row = (lane>>4)*4 + reg   [m89-verified]
    const int rbase = blockIdx.x * 64 + wid * 16 + (lane >> 4) * 4;
#pragma unroll
    for (int r = 0; r < 4; ++r) {
        const int rr = rbase + r;
        if (rr < N) {
            const float sc = rsqrtf((float)max(cnt_out[rr], 1));
            __half* yp = &Y[(size_t)rr * 64 + col];
            yp[0]  = __float2half_rn(acc0[r] * sc);
            yp[16] = __float2half_rn(acc1[r] * sc);
            yp[32] = __float2half_rn(acc2[r] * sc);
            yp[48] = __float2half_rn(acc3[r] * sc);
        }
    }
}

// FUSED layer-1 aggregate + layer-2 GEMM. Block = 32 nodes, 256 threads.
// Phase 1 (8 lanes/node, 16B uint4 gathers, batch-8 clamped):
// h = relu(agg*rs_in+b1), hi/lo fp16 packed into LDS via f16x8 b128 stores
// (64 lanes x 16B = every bank exactly 8-deep, conflict-free).
// B-tile (W2) per wave in 16 VGPRs, loaded after the gather loop.
// Phase 2: wave w computes output col-tile w for both 16-node groups via
// mfma_f32_16x16x32_f16 (3-term hi/lo, fp32 acc), scaled by rs_out -> Y2.
// No early returns (clamped node ids) so barriers stay uniform.
__global__ __launch_bounds__(256)
void agg_gemm_kernel(const __half* __restrict__ Y,
                     const int* __restrict__ row_ptr,
                     const int* __restrict__ csr_src,
                     const int* __restrict__ cnt_in,
                     const int* __restrict__ cnt_out,
                     const float* __restrict__ b1,
                     const float* __restrict__ W2,
                     __half* __restrict__ Y2, int N) {
    __shared__ _Float16 Hh[32][72];
    __shared__ _Float16 Hl[32][72];
    const int t = threadIdx.x;
    const int wid  = t >> 6;
    const int lane = t & 63;
    const int col  = lane & 15;
    const int kg   = (lane >> 4) * 8;

    // ---- phase 1: aggregate, 8 lanes/node ----
    const int nl = t >> 3;                 // local node 0..31
    const int f8 = t & 7;                  // features 8*f8 .. 8*f8+7
    const int n  = blockIdx.x * 32 + nl;
    const int nc = min(n, N - 1);

    const int start = row_ptr[nc];
    const int end   = row_ptr[nc + 1];
    const int last  = end - 1;

    float4 acc0 = {0.f, 0.f, 0.f, 0.f}, acc1 = {0.f, 0.f, 0.f, 0.f};
    for (int e = start; e < end; e += 8) {
        int idx[8];
#pragma unroll
        for (int j = 0; j < 8; ++j) idx[j] = csr_src[min(e + j, last)];
        uint4 v[8];
#pragma unroll
        for (int j = 0; j < 8; ++j)
            v[j] = *((const uint4*)(Y + ((size_t)idx[j] << 6)) + f8);
#pragma unroll
        for (int j = 0; j < 8; ++j) {
            if (e + j < end) {
                float2 a = __half22float2(*(const __half2*)&v[j].x);
                float2 b = __half22float2(*(const __half2*)&v[j].y);
                float2 c = __half22float2(*(const __half2*)&v[j].z);
                float2 d = __half22float2(*(const __half2*)&v[j].w);
                acc0.x += a.x; acc0.y += a.y; acc0.z += b.x; acc0.w += b.y;
                acc1.x += c.x; acc1.y += c.y; acc1.z += d.x; acc1.w += d.y;
            }
        }
    }

    // issue B-tile loads now: W2[k][16*wid+col], k = kg..kg+7 and 32+kg..+7.
    // Latency hides under the H-pack VALU + barrier below.
    float wb[16];
#pragma unroll
    for (int m = 0; m < 8; ++m) {
        wb[m]     = W2[(kg + m) * 64 + 16 * wid + col];
        wb[m + 8] = W2[(32 + kg + m) * 64 + 16 * wid + col];
    }

    {
        const float sc = rsqrtf((float)max(cnt_in[nc], 1));
        const float4 bb0 = *(const float4*)&b1[8 * f8];
        const float4 bb1 = *(const float4*)&b1[8 * f8 + 4];
        float hv[8];
        hv[0] = fmaxf(acc0.x * sc + bb0.x, 0.f);
        hv[1] = fmaxf(acc0.y * sc + bb0.y, 0.f);
        hv[2] = fmaxf(acc0.z * sc + bb0.z, 0.f);
        hv[3] = fmaxf(acc0.w * sc + bb0.w, 0.f);
        hv[4] = fmaxf(acc1.x * sc + bb1.x, 0.f);
        hv[5] = fmaxf(acc1.y * sc + bb1.y, 0.f);
        hv[6] = fmaxf(acc1.z * sc + bb1.z, 0.f);
        hv[7] = fmaxf(acc1.w * sc + bb1.w, 0.f);
        f16x8 hh, hl;
#pragma unroll
        for (int q = 0; q < 8; ++q) {
            const _Float16 hi = (_Float16)hv[q];
            hh[q] = hi;
            hl[q] = (_Float16)(hv[q] - (float)hi);
        }
        *(f16x8*)&Hh[nl][8 * f8] = hh;     // b128 store, banks 8-deep
        *(f16x8*)&Hl[nl][8 * f8] = hl;
    }
    __syncthreads();

    // ---- phase 2: two 16x64 @ 64x64 MFMA groups, wave w -> col tile w ----
    f16x8 bhi0, blo0, bhi1, blo1;
#pragma unroll
    for (int m = 0; m < 8; ++m) {
        _Float16 h = (_Float16)wb[m];
        bhi0[m] = h;
        blo0[m] = (_Float16)(wb[m] - (float)h);
        h = (_Float16)wb[m + 8];
        bhi1[m] = h;
        blo1[m] = (_Float16)(wb[m + 8] - (float)h);
    }

    const int rloc = (lane >> 4) * 4;
#pragma unroll
    for (int g = 0; g < 2; ++g) {
        const f16x8 ahi0 = *(const f16x8*)&Hh[g * 16 + col][kg];
        const f16x8 alo0 = *(const f16x8*)&Hl[g * 16 + col][kg];
        const f16x8 ahi1 = *(const f16x8*)&Hh[g * 16 + col][32 + kg];
        const f16x8 alo1 = *(const f16x8*)&Hl[g * 16 + col][32 + kg];

        f32x4 acc2 = {};
        acc2 = __builtin_amdgcn_mfma_f32_16x16x32_f16(ahi0, bhi0, acc2, 0, 0, 0);
        acc2 = __builtin_amdgcn_mfma_f32_16x16x32_f16(alo0, bhi0, acc2, 0, 0, 0);
        acc2 = __builtin_amdgcn_mfma_f32_16x16x32_f16(ahi0, blo0, acc2, 0, 0, 0);
        acc2 = __builtin_amdgcn_mfma_f32_16x16x32_f16(ahi1, bhi1, acc2, 0, 0, 0);
        acc2 = __builtin_amdgcn_mfma_f32_16x16x32_f16(alo1, bhi1, acc2, 0, 0, 0);
        acc2 = __builtin_amdgcn_mfma_f32_16x16x32_f16(ahi1, blo1, acc2, 0, 0, 0);

        // D layout: col = lane&15, row = (lane>>4)*4 + reg
#pragma unroll
        for (int r = 0; r < 4; ++r) {
            const int rr = blockIdx.x * 32 + g * 16 + rloc + r;
            if (rr < N) {
                const float s2 = rsqrtf((float)max(cnt_out[rr], 1));
                Y2[(size_t)rr * 64 + 16 * wid + col] = __float2half_rn(acc2[r] * s2);
            }
        }
    }
}

// out[n][f] = (sum_{in-edges} Y[src][f]) * rsqrt(max(cnt_in[n],1)) + bias[f]
// 8 lanes per node (8 nodes/wave); lane = 8 features (16B uint4 gather).
// Clamped batch-8: EVERY row runs with 8x16B gathers in flight.
template <bool RELU>
__global__ __launch_bounds__(256)
void aggregate_kernel(const __half* __restrict__ Y,
                      const int* __restrict__ row_ptr,
                      const int* __restrict__ csr_src,
                      const int* __restrict__ cnt_in,
                      const float* __restrict__ bias,
                      float* __restrict__ out, int N) {
    const int n = blockIdx.x * 32 + (threadIdx.x >> 3);
    if (n >= N) return;
    const int f8 = threadIdx.x & 7;           // features 8*f8 .. 8*f8+7

    const int start = row_ptr[n];
    const int end   = row_ptr[n + 1];
    const int last  = end - 1;

    float4 acc0 = {0.f, 0.f, 0.f, 0.f}, acc1 = {0.f, 0.f, 0.f, 0.f};
    for (int e = start; e < end; e += 8) {
        int idx[8];
#pragma unroll
        for (int j = 0; j < 8; ++j) idx[j] = csr_src[min(e + j, last)];
        uint4 v[8];
#pragma unroll
        for (int j = 0; j < 8; ++j)
            v[j] = *((const uint4*)(Y + ((size_t)idx[j] << 6)) + f8);
#pragma unroll
        for (int j = 0; j < 8; ++j) {
            if (e + j < end) {
                float2 a = __half22float2(*(const __half2*)&v[j].x);
                float2 b = __half22float2(*(const __half2*)&v[j].y);
                float2 c = __half22float2(*(const __half2*)&v[j].z);
                float2 d = __half22float2(*(const __half2*)&v[j].w);
                acc0.x += a.x; acc0.y += a.y; acc0.z += b.x; acc0.w += b.y;
                acc1.x += c.x; acc1.y += c.y; acc1.z += d.x; acc1.w += d.y;
            }
        }
    }

    const float sc = rsqrtf((float)max(cnt_in[n], 1));
    const float4 bb0 = *(const float4*)&bias[8 * f8];
    const float4 bb1 = *(const float4*)&bias[8 * f8 + 4];
    float4 o0, o1;
    o0.x = acc0.x * sc + bb0.x;
    o0.y = acc0.y * sc + bb0.y;
    o0.z = acc0.z * sc + bb0.z;
    o0.w = acc0.w * sc + bb0.w;
    o1.x = acc1.x * sc + bb1.x;
    o1.y = acc1.y * sc + bb1.y;
    o1.z = acc1.z * sc + bb1.z;
    o1.w = acc1.w * sc + bb1.w;
    if (RELU) {
        o0.x = fmaxf(o0.x, 0.f); o0.y = fmaxf(o0.y, 0.f);
        o0.z = fmaxf(o0.z, 0.f); o0.w = fmaxf(o0.w, 0.f);
        o1.x = fmaxf(o1.x, 0.f); o1.y = fmaxf(o1.y, 0.f);
        o1.z = fmaxf(o1.z, 0.f); o1.w = fmaxf(o1.w, 0.f);
    }
    float4* op = (float4*)&out[((size_t)n << 6) + 8 * f8];
    op[0] = o0;
    op[1] = o1;
}

extern "C" void kernel_launch(void* const* d_in, const int* in_sizes, int n_in,
                              void* d_out, int out_size, void* d_ws, size_t ws_size,
                              hipStream_t stream) {
    const float* x   = (const float*)d_in[0];
    const int*   src = (const int*)d_in[1];
    const int*   dst = (const int*)d_in[2];
    const float* W1  = (const float*)d_in[3];
    const float* b1  = (const float*)d_in[4];
    const float* W2  = (const float*)d_in[5];
    const float* b2  = (const float*)d_in[6];
    float* out = (float*)d_out;

    const int N = in_sizes[0] / 128;   // 100000
    const int E = in_sizes[1];         // 1600000

    const int nbk = (N + BKT_W - 1) >> BKT_SHIFT;          // 391 buckets

    // Workspace (~45 MB of ~268 MB). d_out written only by the final agg.
    char* ws = (char*)d_ws;
    size_t off = 0;
    __half* Y       = (__half*)(ws + off); off = align256(off + (size_t)N * 64 * sizeof(__half));
    __half* Y2      = (__half*)(ws + off); off = align256(off + (size_t)N * 64 * sizeof(__half));
    int* csr_src    = (int*)(ws + off);    off = align256(off + (size_t)E * sizeof(int));
    int* ebuf       = (int*)(ws + off);    off = align256(off + (size_t)nbk * CAP * sizeof(int));
    unsigned char* sbuf = (unsigned char*)(ws + off); off = align256(off + (size_t)nbk * CAP);
    int* gcnt       = (int*)(ws + off);    off = align256(off + (size_t)2 * nbk * sizeof(int));
    int* gcnt_d     = gcnt;
    int* gcnt_s     = gcnt + nbk;
    int* cnt_out    = (int*)(ws + off);    off = align256(off + (size_t)N * sizeof(int));
    int* cnt_in     = (int*)(ws + off);    off = align256(off + (size_t)N * sizeof(int));
    int* row_ptr    = (int*)(ws + off);    off = align256(off + (size_t)(N + 1) * sizeof(int));

    const int pslice = (E + SC_BLOCKS - 1) / SC_BLOCKS;

    // Single-pass bucket partition (region counters zeroed first, one fill)
    hipMemsetAsync(gcnt, 0, (size_t)2 * nbk * sizeof(int), stream);
    scatter_atomic_kernel<<<SC_BLOCKS, SC_THREADS, 0, stream>>>(
        src, dst, gcnt_d, gcnt_s, ebuf, sbuf, nbk, E, pslice);
    bucket_csr_kernel<<<nbk, 512, 0, stream>>>(ebuf, sbuf, gcnt_d, gcnt_s, csr_src,
                                               cnt_in, cnt_out, row_ptr, nbk, N, E);

    const int gemm_blocks = (N + 63) / 64;
    const int agg_blocks  = (N + 31) / 32;

    // Layer 1 GEMM: Y = fp16[(X @ W1) * rs_out]
    gemm_scale_kernel<128><<<gemm_blocks, 256, 0, stream>>>(x, W1, cnt_out, Y, N);
    // Fused: agg1 (+b1, relu) -> hidden in LDS -> @W2 * rs_out -> Y2 fp16
    agg_gemm_kernel<<<agg_blocks, 256, 0, stream>>>(Y, row_ptr, csr_src,
                                                    cnt_in, cnt_out, b1, W2, Y2, N);
    // Layer 2 aggregate: out = agg(Y2) * rs_in + b2
    aggregate_kernel<false><<<agg_blocks, 256, 0, stream>>>(Y2, row_ptr, csr_src,
                                                            cnt_in, b2, out, N);
}